// Round 1
// baseline (7264.283 us; speedup 1.0000x reference)
//
#include <hip/hip_runtime.h>

#define BS   2048     // B*S tokens
#define DM   1024     // D_MODEL
#define RK   256      // RANK
#define NH   8
#define DH   32
#define NEXP 64       // N_COMPRESS == N_EXPAND
#define NKN  8192     // N_KNOWLEDGE
#define CK   8        // COMPRESS_TOP_K
#define EK   4        // EXPAND_TOP_K
#define KK   8        // KNOWLEDGE_K

#define NEGINF -1e30f

// ---------------- LayerNorm: one block per row of 1024 ----------------
__global__ __launch_bounds__(256) void ln_kernel(const float* __restrict__ xin,
    const float* __restrict__ g, const float* __restrict__ bb, float* __restrict__ out) {
  int row = blockIdx.x, t = threadIdx.x;
  __shared__ float red[256];
  const float4 v = *reinterpret_cast<const float4*>(xin + (size_t)row*DM + t*4);
  red[t] = v.x + v.y + v.z + v.w;
  __syncthreads();
  for (int o = 128; o > 0; o >>= 1) { if (t < o) red[t] += red[t+o]; __syncthreads(); }
  float mu = red[0] * (1.f/DM);
  __syncthreads();
  float dx = v.x-mu, dy = v.y-mu, dz = v.z-mu, dw = v.w-mu;
  red[t] = dx*dx + dy*dy + dz*dz + dw*dw;
  __syncthreads();
  for (int o = 128; o > 0; o >>= 1) { if (t < o) red[t] += red[t+o]; __syncthreads(); }
  float rs = rsqrtf(red[0]*(1.f/DM) + 1e-5f);
  float4 gv = *reinterpret_cast<const float4*>(g + t*4);
  float4 bv = *reinterpret_cast<const float4*>(bb + t*4);
  float4 o4 = make_float4(dx*rs*gv.x+bv.x, dy*rs*gv.y+bv.y, dz*rs*gv.z+bv.z, dw*rs*gv.w+bv.w);
  *reinterpret_cast<float4*>(out + (size_t)row*DM + t*4) = o4;
}

// ------------- Router: scores + top-k + softmax + expert-list append -------------
template<int DIM, int TOPK>
__global__ __launch_bounds__(256) void router_topk(const float* __restrict__ xin,
    const float* __restrict__ rw, float* __restrict__ w_out,
    int* __restrict__ lists, int* __restrict__ counts) {
  int token = blockIdx.x, t = threadIdx.x;
  __shared__ float part[4][64];
  __shared__ float sc[64];
  int n = t & 63, c = t >> 6;
  const int CH = DIM / 4;
  const float* xr = xin + (size_t)token*DIM + c*CH;
  const float* wr = rw  + (size_t)n*DIM + c*CH;
  float p = 0.f;
  for (int j = 0; j < CH; j += 4) {
    float4 a = *reinterpret_cast<const float4*>(xr + j);
    float4 b = *reinterpret_cast<const float4*>(wr + j);
    p += a.x*b.x + a.y*b.y + a.z*b.z + a.w*b.w;
  }
  part[c][n] = p;
  __syncthreads();
  if (t < 64) sc[t] = part[0][t] + part[1][t] + part[2][t] + part[3][t];
  __syncthreads();
  if (t == 0) {
    float tops[TOPK]; int tidx[TOPK];
    for (int k = 0; k < TOPK; ++k) {
      float m = NEGINF; int mi = 0;
      for (int i = 0; i < 64; ++i) { float v = sc[i]; if (v > m) { m = v; mi = i; } }
      tops[k] = m; tidx[k] = mi; sc[mi] = NEGINF;
    }
    float mx = tops[0], se = 0.f, ex[TOPK];
    for (int k = 0; k < TOPK; ++k) { ex[k] = expf(tops[k] - mx); se += ex[k]; }
    float inv = 1.f / se;
    for (int k = 0; k < TOPK; ++k) {
      w_out[token*TOPK + k] = ex[k] * inv;
      int pos = atomicAdd(&counts[tidx[k]], 1);
      lists[tidx[k]*BS + pos] = token*TOPK + k;
    }
  }
}

// ------------- Grouped expert GEMM: out[tok,col] += w * (x[tok] @ W_e) -------------
// grid: (expert, token_chunk, col_chunk of 256). 32 tokens per block.
template<int KDIM, int NCOLT, int TOPK>
__global__ __launch_bounds__(256) void group_gemm(const float* __restrict__ xin,
    const float* __restrict__ neurons, const float* __restrict__ w_all,
    const int* __restrict__ lists, const int* __restrict__ counts,
    float* __restrict__ out) {
  int e = blockIdx.x;
  int cnt = counts[e];
  int base = blockIdx.y * 32;
  if (base >= cnt) return;
  int t = threadIdx.x;
  int col = blockIdx.z * 256 + t;
  __shared__ __align__(16) float xt[32][32];
  __shared__ int   toks[32];
  __shared__ float wts[32];
  if (t < 32) {
    int idx = base + t;
    if (idx < cnt) { int entry = lists[e*BS + idx]; toks[t] = entry / TOPK; wts[t] = w_all[entry]; }
    else           { toks[t] = -1; wts[t] = 0.f; }
  }
  __syncthreads();
  float acc[32];
  #pragma unroll
  for (int i = 0; i < 32; ++i) acc[i] = 0.f;
  const float* W = neurons + (size_t)e * KDIM * NCOLT;
  for (int d0 = 0; d0 < KDIM; d0 += 32) {
    int i = t >> 3, j4 = (t & 7) * 4;
    int tok = toks[i];
    float4 v = (tok >= 0) ? *reinterpret_cast<const float4*>(xin + (size_t)tok*KDIM + d0 + j4)
                          : make_float4(0.f, 0.f, 0.f, 0.f);
    *reinterpret_cast<float4*>(&xt[i][j4]) = v;
    __syncthreads();
    #pragma unroll
    for (int q = 0; q < 8; ++q) {
      int d = d0 + q*4;
      float w0 = W[(size_t)(d+0)*NCOLT + col];
      float w1 = W[(size_t)(d+1)*NCOLT + col];
      float w2 = W[(size_t)(d+2)*NCOLT + col];
      float w3 = W[(size_t)(d+3)*NCOLT + col];
      #pragma unroll
      for (int i2 = 0; i2 < 32; ++i2) {
        const float4 h4 = *reinterpret_cast<const float4*>(&xt[i2][q*4]);
        acc[i2] += h4.x*w0 + h4.y*w1 + h4.z*w2 + h4.w*w3;
      }
    }
    __syncthreads();
  }
  #pragma unroll
  for (int i = 0; i < 32; ++i) {
    if (toks[i] >= 0) atomicAdd(&out[(size_t)toks[i]*NCOLT + col], wts[i]*acc[i]);
  }
}

// ------------- Attention: one block per (q, head, batch) -------------
__global__ __launch_bounds__(256) void attn_kernel(const float* __restrict__ Q,
    const float* __restrict__ K, const float* __restrict__ V, float* __restrict__ AO) {
  int qs = blockIdx.x;
  int hb = blockIdx.y; int h = hb & 7, b = hb >> 3;
  int t = threadIdx.x;
  __shared__ float qv[32];
  __shared__ float sc[512];
  __shared__ float red[256];
  const size_t baseQ = ((size_t)(b*512 + qs))*RK + h*DH;
  if (t < 32) qv[t] = Q[baseQ + t];
  __syncthreads();
  int nk = qs + 1;
  const float scale = 0.17677669529663687f;  // 1/sqrt(32)
  for (int k = t; k < nk; k += 256) {
    const float* kr = K + ((size_t)(b*512 + k))*RK + h*DH;
    float s = 0.f;
    #pragma unroll
    for (int d = 0; d < 32; d += 4) {
      float4 kv = *reinterpret_cast<const float4*>(kr + d);
      s += kv.x*qv[d] + kv.y*qv[d+1] + kv.z*qv[d+2] + kv.w*qv[d+3];
    }
    sc[k] = s * scale;
  }
  __syncthreads();
  float m = NEGINF;
  for (int k = t; k < nk; k += 256) m = fmaxf(m, sc[k]);
  red[t] = m; __syncthreads();
  for (int o = 128; o > 0; o >>= 1) { if (t < o) red[t] = fmaxf(red[t], red[t+o]); __syncthreads(); }
  m = red[0];
  __syncthreads();
  float sloc = 0.f;
  for (int k = t; k < nk; k += 256) { float pp = expf(sc[k] - m); sc[k] = pp; sloc += pp; }
  red[t] = sloc; __syncthreads();
  for (int o = 128; o > 0; o >>= 1) { if (t < o) red[t] += red[t+o]; __syncthreads(); }
  float inv = 1.f / red[0];
  __syncthreads();
  int d = t & 31, c = t >> 5;
  float pa = 0.f;
  for (int k = c; k < nk; k += 8)
    pa += sc[k] * V[((size_t)(b*512 + k))*RK + h*DH + d];
  red[c*32 + d] = pa; __syncthreads();
  if (t < 32) {
    float o = 0.f;
    #pragma unroll
    for (int c2 = 0; c2 < 8; ++c2) o += red[c2*32 + t];
    AO[baseQ + t] = o * inv;
  }
}

// ------------- Transpose knowledge_K [8192][256] -> KT [256][8192] -------------
__global__ __launch_bounds__(256) void transpose_k(const float* __restrict__ kK,
                                                   float* __restrict__ KT) {
  __shared__ float tile[32][33];
  int bx = blockIdx.x, by = blockIdx.y;
  int tx = threadIdx.x & 31, ty = threadIdx.x >> 5;
  for (int r = ty; r < 32; r += 8)
    tile[r][tx] = kK[(size_t)(bx*32 + r)*RK + by*32 + tx];
  __syncthreads();
  for (int r = ty; r < 32; r += 8)
    KT[(size_t)(by*32 + r)*NKN + bx*32 + tx] = tile[tx][r];
}

// ------------- Knowledge: fused scores + running top-8 + softmax + V gather -------------
#define TBT 16
__global__ __launch_bounds__(256) void knowledge_kernel(const float* __restrict__ Qm,
    const float* __restrict__ KT, const float* __restrict__ kV, float* __restrict__ xout) {
  int tok0 = blockIdx.x * TBT;
  int t = threadIdx.x;
  __shared__ __align__(16) float qm[TBT][RK];
  __shared__ float sc[TBT][264];   // 256 chunk scores + 8 running slots
  __shared__ int   ridx[TBT][KK];
  __shared__ float nsc[TBT][KK];
  __shared__ int   nidx[TBT][KK];
  for (int mm = t; mm < TBT*64; mm += 256) {
    int row = mm >> 6, j = (mm & 63) * 4;
    *reinterpret_cast<float4*>(&qm[row][j]) =
        *reinterpret_cast<const float4*>(Qm + (size_t)(tok0 + row)*RK + j);
  }
  if (t < TBT*KK) { sc[t>>3][256 + (t&7)] = NEGINF; ridx[t>>3][t&7] = 0; }
  __syncthreads();
  for (int chunk = 0; chunk < NKN/256; ++chunk) {
    int e = chunk*256 + t;
    float acc[TBT];
    #pragma unroll
    for (int i = 0; i < TBT; ++i) acc[i] = 0.f;
    for (int d = 0; d < RK; d += 4) {
      float k0 = KT[(size_t)(d+0)*NKN + e];
      float k1 = KT[(size_t)(d+1)*NKN + e];
      float k2 = KT[(size_t)(d+2)*NKN + e];
      float k3 = KT[(size_t)(d+3)*NKN + e];
      #pragma unroll
      for (int i = 0; i < TBT; ++i) {
        const float4 q4 = *reinterpret_cast<const float4*>(&qm[i][d]);
        acc[i] += q4.x*k0 + q4.y*k1 + q4.z*k2 + q4.w*k3;
      }
    }
    #pragma unroll
    for (int i = 0; i < TBT; ++i) sc[i][t] = acc[i];
    __syncthreads();
    int wv = t >> 6, lane = t & 63;
    for (int iter = 0; iter < KK; ++iter) {
      #pragma unroll
      for (int s = 0; s < TBT/4; ++s) {
        int tr = wv*(TBT/4) + s;
        float bv = NEGINF; int bp = -1;
        for (int pp = lane; pp < 264; pp += 64) {
          float v = sc[tr][pp];
          if (v > bv) { bv = v; bp = pp; }
        }
        for (int off = 32; off > 0; off >>= 1) {
          float ov = __shfl_down(bv, off);
          int   op = __shfl_down(bp, off);
          if (ov > bv || (ov == bv && (unsigned)op < (unsigned)bp)) { bv = ov; bp = op; }
        }
        if (lane == 0) {
          nsc[tr][iter]  = bv;
          nidx[tr][iter] = (bp < 256) ? (chunk*256 + bp) : ridx[tr][bp - 256];
          sc[tr][bp] = NEGINF;
        }
      }
      __syncthreads();
    }
    if (t < TBT*KK) {
      int r = t >> 3, k = t & 7;
      sc[r][256 + k] = nsc[r][k];
      ridx[r][k] = nidx[r][k];
    }
    __syncthreads();
  }
  if (t < TBT) {
    float mx = sc[t][256] * (1.f/16.f);
    float se = 0.f, ex[KK];
    for (int k = 0; k < KK; ++k) { ex[k] = expf(sc[t][256+k]*(1.f/16.f) - mx); se += ex[k]; }
    float inv = 1.f / se;
    for (int k = 0; k < KK; ++k) nsc[t][k] = ex[k] * inv;
  }
  __syncthreads();
  for (int i = 0; i < TBT; ++i) {
    size_t orow = (size_t)(tok0 + i) * DM;
    float4 o = *reinterpret_cast<const float4*>(xout + orow + t*4);
    #pragma unroll
    for (int k = 0; k < KK; ++k) {
      float w = nsc[i][k];
      const float4 v4 = *reinterpret_cast<const float4*>(kV + (size_t)ridx[i][k]*DM + t*4);
      o.x += w*v4.x; o.y += w*v4.y; o.z += w*v4.z; o.w += w*v4.w;
    }
    *reinterpret_cast<float4*>(xout + orow + t*4) = o;
  }
}

extern "C" void kernel_launch(void* const* d_in, const int* in_sizes, int n_in,
                              void* d_out, int out_size, void* d_ws, size_t ws_size,
                              hipStream_t stream) {
  const float* x  = (const float*)d_in[0];
  // d_in[1] = causal mask (unused; causality hard-coded)
  const float* cn = (const float*)d_in[2];
  const float* en = (const float*)d_in[3];
  const float* kK = (const float*)d_in[4];
  const float* kV = (const float*)d_in[5];
  const float* rq = (const float*)d_in[6];
  const float* rk = (const float*)d_in[7];
  const float* rv = (const float*)d_in[8];
  const float* ro = (const float*)d_in[9];
  const float* rm = (const float*)d_in[10];
  const float* g1 = (const float*)d_in[11];
  const float* b1 = (const float*)d_in[12];
  const float* g2 = (const float*)d_in[13];
  const float* b2 = (const float*)d_in[14];
  float* out = (float*)d_out;

  char* p = (char*)d_ws;
  auto alloc = [&](size_t bytes) { char* r = p; p += (bytes + 255) & ~(size_t)255; return r; };
  float* h   = (float*)alloc((size_t)BS*DM*4);
  float* h2  = (float*)alloc((size_t)BS*DM*4);
  float* KT  = (float*)alloc((size_t)RK*NKN*4);
  float* Q   = (float*)alloc((size_t)BS*RK*4);   // Q,Kb,Vb,Qm contiguous for one memset
  float* Kb  = (float*)alloc((size_t)BS*RK*4);
  float* Vb  = (float*)alloc((size_t)BS*RK*4);
  float* Qm  = (float*)alloc((size_t)BS*RK*4);
  float* AO  = (float*)alloc((size_t)BS*RK*4);
  float* w_q = (float*)alloc((size_t)BS*CK*4);
  float* w_k = (float*)alloc((size_t)BS*CK*4);
  float* w_v = (float*)alloc((size_t)BS*CK*4);
  float* w_m = (float*)alloc((size_t)BS*CK*4);
  float* w_o = (float*)alloc((size_t)BS*EK*4);
  int* lists  = (int*)alloc((size_t)5*64*BS*4);
  int* counts = (int*)alloc((size_t)5*64*4);

  int *listq = lists,          *listk = lists + 1*64*BS, *listv = lists + 2*64*BS,
      *listo = lists + 3*64*BS, *listm = lists + 4*64*BS;
  int *cq = counts, *ckk = counts + 64, *cv = counts + 128, *co = counts + 192, *cm = counts + 256;

  hipMemsetAsync(counts, 0, 5*64*4, stream);
  hipMemsetAsync(Q, 0, (size_t)BS*RK*4*4, stream);  // zeros Q, Kb, Vb, Qm

  ln_kernel<<<BS, 256, 0, stream>>>(x, g1, b1, h);

  router_topk<DM, CK><<<BS, 256, 0, stream>>>(h, rq, w_q, listq, cq);
  router_topk<DM, CK><<<BS, 256, 0, stream>>>(h, rk, w_k, listk, ckk);
  router_topk<DM, CK><<<BS, 256, 0, stream>>>(h, rv, w_v, listv, cv);

  group_gemm<DM, RK, CK><<<dim3(64,64,1), 256, 0, stream>>>(h, cn, w_q, listq, cq, Q);
  group_gemm<DM, RK, CK><<<dim3(64,64,1), 256, 0, stream>>>(h, cn, w_k, listk, ckk, Kb);
  group_gemm<DM, RK, CK><<<dim3(64,64,1), 256, 0, stream>>>(h, cn, w_v, listv, cv, Vb);

  attn_kernel<<<dim3(512, 32), 256, 0, stream>>>(Q, Kb, Vb, AO);

  hipMemcpyAsync(out, x, (size_t)BS*DM*4, hipMemcpyDeviceToDevice, stream);  // out = x

  router_topk<RK, EK><<<BS, 256, 0, stream>>>(AO, ro, w_o, listo, co);
  group_gemm<RK, DM, EK><<<dim3(64,64,4), 256, 0, stream>>>(AO, en, w_o, listo, co, out); // out = x1

  ln_kernel<<<BS, 256, 0, stream>>>(out, g2, b2, h2);
  router_topk<DM, CK><<<BS, 256, 0, stream>>>(h2, rm, w_m, listm, cm);
  group_gemm<DM, RK, CK><<<dim3(64,64,1), 256, 0, stream>>>(h2, cn, w_m, listm, cm, Qm);

  transpose_k<<<dim3(NKN/32, RK/32), 256, 0, stream>>>(kK, KT);
  knowledge_kernel<<<BS/TBT, 256, 0, stream>>>(Qm, KT, kV, out);  // out = x1 + mem_out
}

// Round 2
// 3515.817 us; speedup vs baseline: 2.0662x; 2.0662x over previous
//
#include <hip/hip_runtime.h>

#define BS   2048     // B*S tokens
#define DM   1024     // D_MODEL
#define RK   256      // RANK
#define NH   8
#define DH   32
#define NKN  8192     // N_KNOWLEDGE
#define CK   8        // COMPRESS_TOP_K
#define EK   4        // EXPAND_TOP_K
#define KK   8        // KNOWLEDGE_K
#define KCH  32       // knowledge chunks of 256

#define NEGINF -1e30f

// ---------------- LayerNorm: one block per row of 1024 ----------------
__global__ __launch_bounds__(256) void ln_kernel(const float* __restrict__ xin,
    const float* __restrict__ g, const float* __restrict__ bb, float* __restrict__ out) {
  int row = blockIdx.x, t = threadIdx.x;
  __shared__ float red[256];
  const float4 v = *reinterpret_cast<const float4*>(xin + (size_t)row*DM + t*4);
  red[t] = v.x + v.y + v.z + v.w;
  __syncthreads();
  for (int o = 128; o > 0; o >>= 1) { if (t < o) red[t] += red[t+o]; __syncthreads(); }
  float mu = red[0] * (1.f/DM);
  __syncthreads();
  float dx = v.x-mu, dy = v.y-mu, dz = v.z-mu, dw = v.w-mu;
  red[t] = dx*dx + dy*dy + dz*dz + dw*dw;
  __syncthreads();
  for (int o = 128; o > 0; o >>= 1) { if (t < o) red[t] += red[t+o]; __syncthreads(); }
  float rs = rsqrtf(red[0]*(1.f/DM) + 1e-5f);
  float4 gv = *reinterpret_cast<const float4*>(g + t*4);
  float4 bv = *reinterpret_cast<const float4*>(bb + t*4);
  float4 o4 = make_float4(dx*rs*gv.x+bv.x, dy*rs*gv.y+bv.y, dz*rs*gv.z+bv.z, dw*rs*gv.w+bv.w);
  *reinterpret_cast<float4*>(out + (size_t)row*DM + t*4) = o4;
}

// ---- wave-parallel top-k over 64 scores held one-per-lane (t = lane 0..63) ----
// After call, tops[]/tidx[] valid on ALL lanes (xor-butterfly broadcast).
template<int TOPK>
__device__ inline void wave_topk64(float bv, int lane, float* tops, int* tidx) {
  #pragma unroll
  for (int k = 0; k < TOPK; ++k) {
    float mv = bv; int mp = lane;
    #pragma unroll
    for (int off = 32; off > 0; off >>= 1) {
      float ov = __shfl_xor(mv, off); int op = __shfl_xor(mp, off);
      if (ov > mv || (ov == mv && op < mp)) { mv = ov; mp = op; }
    }
    tops[k] = mv; tidx[k] = mp;
    if (lane == mp) bv = NEGINF;
  }
}

// ------------- Generic router: scores + wave top-k + softmax + list append -------------
template<int DIM, int TOPK>
__global__ __launch_bounds__(256) void router_topk(const float* __restrict__ xin,
    const float* __restrict__ rw, float* __restrict__ w_out,
    int* __restrict__ lists, int* __restrict__ counts) {
  int token = blockIdx.x, t = threadIdx.x;
  __shared__ float part[4][64];
  int n = t & 63, c = t >> 6;
  const int CH = DIM / 4;
  const float* xr = xin + (size_t)token*DIM + c*CH;
  const float* wr = rw  + (size_t)n*DIM + c*CH;
  float p = 0.f;
  for (int j = 0; j < CH; j += 4) {
    float4 a = *reinterpret_cast<const float4*>(xr + j);
    float4 b = *reinterpret_cast<const float4*>(wr + j);
    p += a.x*b.x + a.y*b.y + a.z*b.z + a.w*b.w;
  }
  part[c][n] = p;
  __syncthreads();
  if (t < 64) {
    float bv = part[0][t] + part[1][t] + part[2][t] + part[3][t];
    float tops[TOPK]; int tidx[TOPK];
    wave_topk64<TOPK>(bv, t, tops, tidx);
    if (t == 0) {
      float mx = tops[0], se = 0.f, ex[TOPK];
      #pragma unroll
      for (int k = 0; k < TOPK; ++k) { ex[k] = expf(tops[k] - mx); se += ex[k]; }
      float inv = 1.f / se;
      #pragma unroll
      for (int k = 0; k < TOPK; ++k) {
        w_out[token*TOPK + k] = ex[k] * inv;
        int pos = atomicAdd(&counts[tidx[k]], 1);
        lists[tidx[k]*BS + pos] = token*TOPK + k;
      }
    }
  }
}

// ------------- Fused QKV router: reads h once, 3 waves do 3 selections -------------
__global__ __launch_bounds__(256) void router3(const float* __restrict__ xin,
    const float* __restrict__ w0, const float* __restrict__ w1, const float* __restrict__ w2,
    float* __restrict__ w_all,        // [3][BS*CK]
    int* __restrict__ lists,          // [3][64][BS]
    int* __restrict__ counts) {       // [3][64]
  int token = blockIdx.x, t = threadIdx.x;
  __shared__ float part[3][4][64];
  int n = t & 63, c = t >> 6;
  const int CH = DM / 4;
  const float* xr = xin + (size_t)token*DM + c*CH;
  const float* a0 = w0 + (size_t)n*DM + c*CH;
  const float* a1 = w1 + (size_t)n*DM + c*CH;
  const float* a2 = w2 + (size_t)n*DM + c*CH;
  float p0 = 0.f, p1 = 0.f, p2 = 0.f;
  for (int j = 0; j < CH; j += 4) {
    float4 a  = *reinterpret_cast<const float4*>(xr + j);
    float4 b0 = *reinterpret_cast<const float4*>(a0 + j);
    float4 b1 = *reinterpret_cast<const float4*>(a1 + j);
    float4 b2 = *reinterpret_cast<const float4*>(a2 + j);
    p0 += a.x*b0.x + a.y*b0.y + a.z*b0.z + a.w*b0.w;
    p1 += a.x*b1.x + a.y*b1.y + a.z*b1.z + a.w*b1.w;
    p2 += a.x*b2.x + a.y*b2.y + a.z*b2.z + a.w*b2.w;
  }
  part[0][c][n] = p0; part[1][c][n] = p1; part[2][c][n] = p2;
  __syncthreads();
  int wv = t >> 6, lane = t & 63;
  if (wv < 3) {
    float bv = part[wv][0][lane] + part[wv][1][lane] + part[wv][2][lane] + part[wv][3][lane];
    float tops[CK]; int tidx[CK];
    wave_topk64<CK>(bv, lane, tops, tidx);
    if (lane == 0) {
      float* wo = w_all + (size_t)wv*BS*CK;
      int* lst  = lists  + (size_t)wv*64*BS;
      int* cnt  = counts + wv*64;
      float mx = tops[0], se = 0.f, ex[CK];
      #pragma unroll
      for (int k = 0; k < CK; ++k) { ex[k] = expf(tops[k] - mx); se += ex[k]; }
      float inv = 1.f / se;
      #pragma unroll
      for (int k = 0; k < CK; ++k) {
        wo[token*CK + k] = ex[k] * inv;
        int pos = atomicAdd(&cnt[tidx[k]], 1);
        lst[tidx[k]*BS + pos] = token*CK + k;
      }
    }
  }
}

// ------------- Grouped expert GEMM body (shared by single and x3 variants) -------------
template<int KDIM, int NCOLT, int TOPK>
__device__ inline void group_gemm_body(const float* __restrict__ xin,
    const float* __restrict__ W, const float* __restrict__ w_all,
    const int* __restrict__ list_e, int cnt, int base, float* __restrict__ out) {
  int t = threadIdx.x;
  int col = blockIdx.y % (NCOLT/256) == 0 ? 0 : 0;  // placeholder (col computed by caller layout)
  (void)col;
  __shared__ __align__(16) float xt[32][32];
  __shared__ int   toks[32];
  __shared__ float wts[32];
  if (t < 32) {
    int idx = base + t;
    if (idx < cnt) { int entry = list_e[idx]; toks[t] = entry / TOPK; wts[t] = w_all[entry]; }
    else           { toks[t] = -1; wts[t] = 0.f; }
  }
  __syncthreads();
  float acc[32];
  #pragma unroll
  for (int i = 0; i < 32; ++i) acc[i] = 0.f;
  int colg = (blockIdx.y & ((NCOLT/256) - 1)) * 256 + t;  // col within NCOLT
  for (int d0 = 0; d0 < KDIM; d0 += 32) {
    int i = t >> 3, j4 = (t & 7) * 4;
    int tok = toks[i];
    float4 v = (tok >= 0) ? *reinterpret_cast<const float4*>(xin + (size_t)tok*KDIM + d0 + j4)
                          : make_float4(0.f, 0.f, 0.f, 0.f);
    *reinterpret_cast<float4*>(&xt[i][j4]) = v;
    __syncthreads();
    #pragma unroll
    for (int q = 0; q < 8; ++q) {
      int d = d0 + q*4;
      float w0 = W[(size_t)(d+0)*NCOLT + colg];
      float w1 = W[(size_t)(d+1)*NCOLT + colg];
      float w2 = W[(size_t)(d+2)*NCOLT + colg];
      float w3 = W[(size_t)(d+3)*NCOLT + colg];
      #pragma unroll
      for (int i2 = 0; i2 < 32; ++i2) {
        const float4 h4 = *reinterpret_cast<const float4*>(&xt[i2][q*4]);
        acc[i2] += h4.x*w0 + h4.y*w1 + h4.z*w2 + h4.w*w3;
      }
    }
    __syncthreads();
  }
  #pragma unroll
  for (int i = 0; i < 32; ++i) {
    if (toks[i] >= 0) atomicAdd(&out[(size_t)toks[i]*NCOLT + colg], wts[i]*acc[i]);
  }
}

// grid: (expert, token_chunk * col_chunks). One routed matrix.
template<int KDIM, int NCOLT, int TOPK>
__global__ __launch_bounds__(256) void group_gemm(const float* __restrict__ xin,
    const float* __restrict__ neurons, const float* __restrict__ w_all,
    const int* __restrict__ lists, const int* __restrict__ counts,
    float* __restrict__ out) {
  int e = blockIdx.x;
  int cnt = counts[e];
  int base = (blockIdx.y / (NCOLT/256)) * 32;
  if (base >= cnt) return;
  group_gemm_body<KDIM, NCOLT, TOPK>(xin, neurons + (size_t)e*KDIM*NCOLT,
                                     w_all, lists + (size_t)e*BS, cnt, base, out);
}

// grid: (expert, token_chunk, 3). Q/K/V in one dispatch (same x, same neurons).
template<int KDIM, int NCOLT, int TOPK>
__global__ __launch_bounds__(256) void group_gemm3(const float* __restrict__ xin,
    const float* __restrict__ neurons, const float* __restrict__ w_all,  // [3][BS*TOPK]
    const int* __restrict__ lists,      // [3][64][BS]
    const int* __restrict__ counts,     // [3][64]
    float* __restrict__ out) {          // [3][BS][NCOLT] contiguous
  int e = blockIdx.x, which = blockIdx.z;
  int cnt = counts[which*64 + e];
  int base = blockIdx.y * 32;
  if (base >= cnt) return;
  group_gemm_body<KDIM, NCOLT, TOPK>(xin, neurons + (size_t)e*KDIM*NCOLT,
                                     w_all + (size_t)which*BS*TOPK,
                                     lists + ((size_t)which*64 + e)*BS, cnt, base,
                                     out + (size_t)which*BS*NCOLT);
}

// ------------- Attention: one block per (q, head*batch) -------------
__global__ __launch_bounds__(256) void attn_kernel(const float* __restrict__ Q,
    const float* __restrict__ K, const float* __restrict__ V, float* __restrict__ AO) {
  int qs = blockIdx.x;
  int hb = blockIdx.y; int h = hb & 7, b = hb >> 3;
  int t = threadIdx.x;
  __shared__ float qv[32];
  __shared__ float sc[512];
  __shared__ float red[256];
  const size_t baseQ = ((size_t)(b*512 + qs))*RK + h*DH;
  if (t < 32) qv[t] = Q[baseQ + t];
  __syncthreads();
  int nk = qs + 1;
  const float scale = 0.17677669529663687f;  // 1/sqrt(32)
  for (int k = t; k < nk; k += 256) {
    const float* kr = K + ((size_t)(b*512 + k))*RK + h*DH;
    float s = 0.f;
    #pragma unroll
    for (int d = 0; d < 32; d += 4) {
      float4 kv = *reinterpret_cast<const float4*>(kr + d);
      s += kv.x*qv[d] + kv.y*qv[d+1] + kv.z*qv[d+2] + kv.w*qv[d+3];
    }
    sc[k] = s * scale;
  }
  __syncthreads();
  float m = NEGINF;
  for (int k = t; k < nk; k += 256) m = fmaxf(m, sc[k]);
  red[t] = m; __syncthreads();
  for (int o = 128; o > 0; o >>= 1) { if (t < o) red[t] = fmaxf(red[t], red[t+o]); __syncthreads(); }
  m = red[0];
  __syncthreads();
  float sloc = 0.f;
  for (int k = t; k < nk; k += 256) { float pp = expf(sc[k] - m); sc[k] = pp; sloc += pp; }
  red[t] = sloc; __syncthreads();
  for (int o = 128; o > 0; o >>= 1) { if (t < o) red[t] += red[t+o]; __syncthreads(); }
  float inv = 1.f / red[0];
  __syncthreads();
  int d = t & 31, c = t >> 5;
  float pa = 0.f;
  for (int k = c; k < nk; k += 8)
    pa += sc[k] * V[((size_t)(b*512 + k))*RK + h*DH + d];
  red[c*32 + d] = pa; __syncthreads();
  if (t < 32) {
    float o = 0.f;
    #pragma unroll
    for (int c2 = 0; c2 < 8; ++c2) o += red[c2*32 + t];
    AO[baseQ + t] = o * inv;
  }
}

// ------------- Transpose knowledge_K [8192][256] -> KT [256][8192] -------------
__global__ __launch_bounds__(256) void transpose_k(const float* __restrict__ kK,
                                                   float* __restrict__ KT) {
  __shared__ float tile[32][33];
  int bx = blockIdx.x, by = blockIdx.y;
  int tx = threadIdx.x & 31, ty = threadIdx.x >> 5;
  for (int r = ty; r < 32; r += 8)
    tile[r][tx] = kK[(size_t)(bx*32 + r)*RK + by*32 + tx];
  __syncthreads();
  for (int r = ty; r < 32; r += 8)
    KT[(size_t)(by*32 + r)*NKN + bx*32 + tx] = tile[tx][r];
}

// ------------- Knowledge pass 1: scores for one chunk + per-chunk top-8 -------------
// grid: (32 chunks, 128 token-tiles of 16)
__global__ __launch_bounds__(256) void knowledge_score(const float* __restrict__ Qm,
    const float* __restrict__ KT, float* __restrict__ cand_s, int* __restrict__ cand_i) {
  int chunk = blockIdx.x, tile = blockIdx.y, t = threadIdx.x;
  __shared__ __align__(16) float qm[16][RK];
  __shared__ float sc[16][256];
  for (int mm = t; mm < 16*64; mm += 256) {
    int row = mm >> 6, j = (mm & 63) * 4;
    *reinterpret_cast<float4*>(&qm[row][j]) =
        *reinterpret_cast<const float4*>(Qm + (size_t)(tile*16 + row)*RK + j);
  }
  __syncthreads();
  int e = chunk*256 + t;
  float acc[16];
  #pragma unroll
  for (int i = 0; i < 16; ++i) acc[i] = 0.f;
  for (int d = 0; d < RK; d += 4) {
    float k0 = KT[(size_t)(d+0)*NKN + e];
    float k1 = KT[(size_t)(d+1)*NKN + e];
    float k2 = KT[(size_t)(d+2)*NKN + e];
    float k3 = KT[(size_t)(d+3)*NKN + e];
    #pragma unroll
    for (int i = 0; i < 16; ++i) {
      const float4 q4 = *reinterpret_cast<const float4*>(&qm[i][d]);
      acc[i] += q4.x*k0 + q4.y*k1 + q4.z*k2 + q4.w*k3;
    }
  }
  #pragma unroll
  for (int i = 0; i < 16; ++i) sc[i][t] = acc[i];
  __syncthreads();
  int wv = t >> 6, lane = t & 63;
  #pragma unroll
  for (int s = 0; s < 4; ++s) {
    int tok = wv*4 + s;
    float v0 = sc[tok][lane], v1 = sc[tok][lane+64], v2 = sc[tok][lane+128], v3 = sc[tok][lane+192];
    size_t cbase = ((size_t)(tile*16 + tok)*KCH + chunk)*KK;
    #pragma unroll
    for (int iter = 0; iter < KK; ++iter) {
      float mv = v0; int mp = lane;
      if (v1 > mv) { mv = v1; mp = lane+64; }
      if (v2 > mv) { mv = v2; mp = lane+128; }
      if (v3 > mv) { mv = v3; mp = lane+192; }
      #pragma unroll
      for (int off = 32; off > 0; off >>= 1) {
        float ov = __shfl_xor(mv, off); int op = __shfl_xor(mp, off);
        if (ov > mv || (ov == mv && op < mp)) { mv = ov; mp = op; }
      }
      if ((mp & 63) == lane) {
        int j = mp >> 6;
        if (j == 0) v0 = NEGINF; else if (j == 1) v1 = NEGINF;
        else if (j == 2) v2 = NEGINF; else v3 = NEGINF;
      }
      if (lane == 0) { cand_s[cbase + iter] = mv; cand_i[cbase + iter] = chunk*256 + mp; }
    }
  }
}

// ------------- Knowledge pass 2: merge 256 candidates -> top-8, softmax, V gather -------------
__global__ __launch_bounds__(256) void knowledge_merge(const float* __restrict__ cand_s,
    const int* __restrict__ cand_i, const float* __restrict__ kV, float* __restrict__ xout) {
  int tok = blockIdx.x, t = threadIdx.x;
  __shared__ float s_sc[256];
  __shared__ int   s_ix[256];
  __shared__ float w8[KK];
  __shared__ int   i8[KK];
  s_sc[t] = cand_s[(size_t)tok*256 + t];
  s_ix[t] = cand_i[(size_t)tok*256 + t];
  __syncthreads();
  if (t < 64) {
    float v0 = s_sc[t], v1 = s_sc[t+64], v2 = s_sc[t+128], v3 = s_sc[t+192];
    float tops[KK]; int tpos[KK];
    #pragma unroll
    for (int iter = 0; iter < KK; ++iter) {
      float mv = v0; int mp = t;
      if (v1 > mv) { mv = v1; mp = t+64; }
      if (v2 > mv) { mv = v2; mp = t+128; }
      if (v3 > mv) { mv = v3; mp = t+192; }
      #pragma unroll
      for (int off = 32; off > 0; off >>= 1) {
        float ov = __shfl_xor(mv, off); int op = __shfl_xor(mp, off);
        if (ov > mv || (ov == mv && op < mp)) { mv = ov; mp = op; }
      }
      tops[iter] = mv; tpos[iter] = mp;
      if ((mp & 63) == t) {
        int j = mp >> 6;
        if (j == 0) v0 = NEGINF; else if (j == 1) v1 = NEGINF;
        else if (j == 2) v2 = NEGINF; else v3 = NEGINF;
      }
    }
    if (t == 0) {
      const float kscale = 1.f/16.f;  // 1/sqrt(256)
      float mx = tops[0]*kscale, se = 0.f, ex[KK];
      #pragma unroll
      for (int k = 0; k < KK; ++k) { ex[k] = expf(tops[k]*kscale - mx); se += ex[k]; }
      float inv = 1.f / se;
      #pragma unroll
      for (int k = 0; k < KK; ++k) { w8[k] = ex[k]*inv; i8[k] = s_ix[tpos[k]]; }
    }
  }
  __syncthreads();
  size_t orow = (size_t)tok * DM;
  float4 o = *reinterpret_cast<const float4*>(xout + orow + t*4);
  #pragma unroll
  for (int k = 0; k < KK; ++k) {
    float w = w8[k];
    const float4 v4 = *reinterpret_cast<const float4*>(kV + (size_t)i8[k]*DM + t*4);
    o.x += w*v4.x; o.y += w*v4.y; o.z += w*v4.z; o.w += w*v4.w;
  }
  *reinterpret_cast<float4*>(xout + orow + t*4) = o;
}

extern "C" void kernel_launch(void* const* d_in, const int* in_sizes, int n_in,
                              void* d_out, int out_size, void* d_ws, size_t ws_size,
                              hipStream_t stream) {
  const float* x  = (const float*)d_in[0];
  // d_in[1] = causal mask (unused; causality hard-coded)
  const float* cn = (const float*)d_in[2];
  const float* en = (const float*)d_in[3];
  const float* kK = (const float*)d_in[4];
  const float* kV = (const float*)d_in[5];
  const float* rq = (const float*)d_in[6];
  const float* rk = (const float*)d_in[7];
  const float* rv = (const float*)d_in[8];
  const float* ro = (const float*)d_in[9];
  const float* rm = (const float*)d_in[10];
  const float* g1 = (const float*)d_in[11];
  const float* b1 = (const float*)d_in[12];
  const float* g2 = (const float*)d_in[13];
  const float* b2 = (const float*)d_in[14];
  float* out = (float*)d_out;

  char* p = (char*)d_ws;
  auto alloc = [&](size_t bytes) { char* r = p; p += (bytes + 255) & ~(size_t)255; return r; };
  float* h    = (float*)alloc((size_t)BS*DM*4);
  float* h2   = (float*)alloc((size_t)BS*DM*4);
  float* KT   = (float*)alloc((size_t)RK*NKN*4);
  float* Q    = (float*)alloc((size_t)BS*RK*4);   // Q,Kb,Vb contiguous (group_gemm3 out)
  float* Kb   = (float*)alloc((size_t)BS*RK*4);
  float* Vb   = (float*)alloc((size_t)BS*RK*4);
  float* Qm   = (float*)alloc((size_t)BS*RK*4);
  float* AO   = (float*)alloc((size_t)BS*RK*4);
  float* w_all= (float*)alloc((size_t)3*BS*CK*4); // q,k,v router weights contiguous
  float* w_o  = (float*)alloc((size_t)BS*EK*4);
  float* w_m  = (float*)alloc((size_t)BS*CK*4);
  float* cand_s = (float*)alloc((size_t)BS*KCH*KK*4);
  int*   cand_i = (int*)  alloc((size_t)BS*KCH*KK*4);
  int* lists  = (int*)alloc((size_t)5*64*BS*4);   // [q,k,v,o,m]
  int* counts = (int*)alloc((size_t)5*64*4);

  int *listo = lists + 3*64*BS, *listm = lists + 4*64*BS;
  int *co = counts + 192, *cm = counts + 256;

  hipMemsetAsync(counts, 0, 5*64*4, stream);
  hipMemsetAsync(Q, 0, (size_t)BS*RK*4*4, stream);  // zeros Q, Kb, Vb, Qm

  ln_kernel<<<BS, 256, 0, stream>>>(x, g1, b1, h);

  router3<<<BS, 256, 0, stream>>>(h, rq, rk, rv, w_all, lists, counts);
  group_gemm3<DM, RK, CK><<<dim3(64,64,3), 256, 0, stream>>>(h, cn, w_all, lists, counts, Q);

  attn_kernel<<<dim3(512, 32), 256, 0, stream>>>(Q, Kb, Vb, AO);

  hipMemcpyAsync(out, x, (size_t)BS*DM*4, hipMemcpyDeviceToDevice, stream);  // out = x

  router_topk<RK, EK><<<BS, 256, 0, stream>>>(AO, ro, w_o, listo, co);
  group_gemm<RK, DM, EK><<<dim3(64, 64*4), 256, 0, stream>>>(AO, en, w_o, listo, co, out); // out = x1

  ln_kernel<<<BS, 256, 0, stream>>>(out, g2, b2, h2);
  router_topk<DM, CK><<<BS, 256, 0, stream>>>(h2, rm, w_m, listm, cm);
  group_gemm<DM, RK, CK><<<dim3(64, 64), 256, 0, stream>>>(h2, cn, w_m, listm, cm, Qm);

  transpose_k<<<dim3(NKN/32, RK/32), 256, 0, stream>>>(kK, KT);
  knowledge_score<<<dim3(KCH, BS/16), 256, 0, stream>>>(Qm, KT, cand_s, cand_i);
  knowledge_merge<<<BS, 256, 0, stream>>>(cand_s, cand_i, kV, out);  // out = x1 + mem_out
}

// Round 3
// 2936.844 us; speedup vs baseline: 2.4735x; 1.1971x over previous
//
#include <hip/hip_runtime.h>

#define BS   2048     // B*S tokens
#define DM   1024     // D_MODEL
#define RK   256      // RANK
#define NH   8
#define DH   32
#define NKN  8192     // N_KNOWLEDGE
#define CK   8        // COMPRESS_TOP_K
#define EK   4        // EXPAND_TOP_K
#define KK   8        // KNOWLEDGE_K
#define KCH  32       // knowledge chunks of 256

#define NEGINF -1e30f

// ---------------- LayerNorm: one block per row of 1024 ----------------
__global__ __launch_bounds__(256) void ln_kernel(const float* __restrict__ xin,
    const float* __restrict__ g, const float* __restrict__ bb, float* __restrict__ out) {
  int row = blockIdx.x, t = threadIdx.x;
  __shared__ float red[256];
  const float4 v = *reinterpret_cast<const float4*>(xin + (size_t)row*DM + t*4);
  red[t] = v.x + v.y + v.z + v.w;
  __syncthreads();
  for (int o = 128; o > 0; o >>= 1) { if (t < o) red[t] += red[t+o]; __syncthreads(); }
  float mu = red[0] * (1.f/DM);
  __syncthreads();
  float dx = v.x-mu, dy = v.y-mu, dz = v.z-mu, dw = v.w-mu;
  red[t] = dx*dx + dy*dy + dz*dz + dw*dw;
  __syncthreads();
  for (int o = 128; o > 0; o >>= 1) { if (t < o) red[t] += red[t+o]; __syncthreads(); }
  float rs = rsqrtf(red[0]*(1.f/DM) + 1e-5f);
  float4 gv = *reinterpret_cast<const float4*>(g + t*4);
  float4 bv = *reinterpret_cast<const float4*>(bb + t*4);
  float4 o4 = make_float4(dx*rs*gv.x+bv.x, dy*rs*gv.y+bv.y, dz*rs*gv.z+bv.z, dw*rs*gv.w+bv.w);
  *reinterpret_cast<float4*>(out + (size_t)row*DM + t*4) = o4;
}

// ---- wave-parallel top-k over 64 scores held one-per-lane ----
template<int TOPK>
__device__ inline void wave_topk64(float bv, int lane, float* tops, int* tidx) {
  #pragma unroll
  for (int k = 0; k < TOPK; ++k) {
    float mv = bv; int mp = lane;
    #pragma unroll
    for (int off = 32; off > 0; off >>= 1) {
      float ov = __shfl_xor(mv, off); int op = __shfl_xor(mp, off);
      if (ov > mv || (ov == mv && op < mp)) { mv = ov; mp = op; }
    }
    tops[k] = mv; tidx[k] = mp;
    if (lane == mp) bv = NEGINF;
  }
}

// ------------- Generic router -------------
template<int DIM, int TOPK>
__global__ __launch_bounds__(256) void router_topk(const float* __restrict__ xin,
    const float* __restrict__ rw, float* __restrict__ w_out,
    int* __restrict__ lists, int* __restrict__ counts) {
  int token = blockIdx.x, t = threadIdx.x;
  __shared__ float part[4][64];
  int n = t & 63, c = t >> 6;
  const int CH = DIM / 4;
  const float* xr = xin + (size_t)token*DIM + c*CH;
  const float* wr = rw  + (size_t)n*DIM + c*CH;
  float p = 0.f;
  for (int j = 0; j < CH; j += 4) {
    float4 a = *reinterpret_cast<const float4*>(xr + j);
    float4 b = *reinterpret_cast<const float4*>(wr + j);
    p += a.x*b.x + a.y*b.y + a.z*b.z + a.w*b.w;
  }
  part[c][n] = p;
  __syncthreads();
  if (t < 64) {
    float bv = part[0][t] + part[1][t] + part[2][t] + part[3][t];
    float tops[TOPK]; int tidx[TOPK];
    wave_topk64<TOPK>(bv, t, tops, tidx);
    if (t == 0) {
      float mx = tops[0], se = 0.f, ex[TOPK];
      #pragma unroll
      for (int k = 0; k < TOPK; ++k) { ex[k] = expf(tops[k] - mx); se += ex[k]; }
      float inv = 1.f / se;
      #pragma unroll
      for (int k = 0; k < TOPK; ++k) {
        w_out[token*TOPK + k] = ex[k] * inv;
        int pos = atomicAdd(&counts[tidx[k]], 1);
        lists[tidx[k]*BS + pos] = token*TOPK + k;
      }
    }
  }
}

// ------------- Fused QKV router -------------
__global__ __launch_bounds__(256) void router3(const float* __restrict__ xin,
    const float* __restrict__ w0, const float* __restrict__ w1, const float* __restrict__ w2,
    float* __restrict__ w_all, int* __restrict__ lists, int* __restrict__ counts) {
  int token = blockIdx.x, t = threadIdx.x;
  __shared__ float part[3][4][64];
  int n = t & 63, c = t >> 6;
  const int CH = DM / 4;
  const float* xr = xin + (size_t)token*DM + c*CH;
  const float* a0 = w0 + (size_t)n*DM + c*CH;
  const float* a1 = w1 + (size_t)n*DM + c*CH;
  const float* a2 = w2 + (size_t)n*DM + c*CH;
  float p0 = 0.f, p1 = 0.f, p2 = 0.f;
  for (int j = 0; j < CH; j += 4) {
    float4 a  = *reinterpret_cast<const float4*>(xr + j);
    float4 b0 = *reinterpret_cast<const float4*>(a0 + j);
    float4 b1 = *reinterpret_cast<const float4*>(a1 + j);
    float4 b2 = *reinterpret_cast<const float4*>(a2 + j);
    p0 += a.x*b0.x + a.y*b0.y + a.z*b0.z + a.w*b0.w;
    p1 += a.x*b1.x + a.y*b1.y + a.z*b1.z + a.w*b1.w;
    p2 += a.x*b2.x + a.y*b2.y + a.z*b2.z + a.w*b2.w;
  }
  part[0][c][n] = p0; part[1][c][n] = p1; part[2][c][n] = p2;
  __syncthreads();
  int wv = t >> 6, lane = t & 63;
  if (wv < 3) {
    float bv = part[wv][0][lane] + part[wv][1][lane] + part[wv][2][lane] + part[wv][3][lane];
    float tops[CK]; int tidx[CK];
    wave_topk64<CK>(bv, lane, tops, tidx);
    if (lane == 0) {
      float* wo = w_all + (size_t)wv*BS*CK;
      int* lst  = lists  + (size_t)wv*64*BS;
      int* cnt  = counts + wv*64;
      float mx = tops[0], se = 0.f, ex[CK];
      #pragma unroll
      for (int k = 0; k < CK; ++k) { ex[k] = expf(tops[k] - mx); se += ex[k]; }
      float inv = 1.f / se;
      #pragma unroll
      for (int k = 0; k < CK; ++k) {
        wo[token*CK + k] = ex[k] * inv;
        int pos = atomicAdd(&cnt[tidx[k]], 1);
        lst[tidx[k]*BS + pos] = token*CK + k;
      }
    }
  }
}

// ------------- Grouped expert GEMM, register-tiled -------------
// Block tile: 64 tokens x 256 cols. Thread: 16 tokens x 4 cols (acc[16][4]).
// 4 waves (ty) each own 16 tokens; cols = colbase + tx + c*64.
template<int KDIM, int NCOLT, int TOPK>
__device__ inline void ggemm_body(const float* __restrict__ xin,
    const float* __restrict__ W, const float* __restrict__ w_all,
    const int* __restrict__ list_e, int cnt, int base, int colbase,
    float* __restrict__ out) {
  int t = threadIdx.x;
  int tx = t & 63, ty = t >> 6;
  __shared__ __align__(16) float xt[64][32];
  __shared__ int   toks[64];
  __shared__ float wts[64];
  if (t < 64) {
    int idx = base + t;
    if (idx < cnt) { int e2 = list_e[idx]; toks[t] = e2 / TOPK; wts[t] = w_all[e2]; }
    else           { toks[t] = -1; wts[t] = 0.f; }
  }
  __syncthreads();
  float acc[16][4];
  #pragma unroll
  for (int i = 0; i < 16; ++i)
    #pragma unroll
    for (int c = 0; c < 4; ++c) acc[i][c] = 0.f;
  int col = colbase + tx;
  for (int d0 = 0; d0 < KDIM; d0 += 32) {
    #pragma unroll
    for (int l0 = 0; l0 < 512; l0 += 256) {
      int l = l0 + t;
      int tok = l >> 3, j4 = (l & 7) * 4;
      int tk = toks[tok];
      float4 v = (tk >= 0) ? *reinterpret_cast<const float4*>(xin + (size_t)tk*KDIM + d0 + j4)
                           : make_float4(0.f, 0.f, 0.f, 0.f);
      *reinterpret_cast<float4*>(&xt[tok][j4]) = v;
    }
    __syncthreads();
    #pragma unroll
    for (int q = 0; q < 8; ++q) {
      const float* Wr = W + (size_t)(d0 + q*4)*NCOLT + col;
      float w[4][4];
      #pragma unroll
      for (int kk = 0; kk < 4; ++kk)
        #pragma unroll
        for (int c = 0; c < 4; ++c)
          w[kk][c] = Wr[(size_t)kk*NCOLT + c*64];
      #pragma unroll
      for (int i = 0; i < 16; ++i) {
        const float4 x4 = *reinterpret_cast<const float4*>(&xt[ty*16 + i][q*4]);
        #pragma unroll
        for (int c = 0; c < 4; ++c)
          acc[i][c] = fmaf(x4.w, w[3][c], fmaf(x4.z, w[2][c],
                      fmaf(x4.y, w[1][c], fmaf(x4.x, w[0][c], acc[i][c]))));
      }
    }
    __syncthreads();
  }
  #pragma unroll
  for (int i = 0; i < 16; ++i) {
    int tok = toks[ty*16 + i];
    if (tok >= 0) {
      float wt = wts[ty*16 + i];
      #pragma unroll
      for (int c = 0; c < 4; ++c)
        atomicAdd(&out[(size_t)tok*NCOLT + col + c*64], wt * acc[i][c]);
    }
  }
}

// grid: (expert, token_chunk * col_chunks)
template<int KDIM, int NCOLT, int TOPK>
__global__ __launch_bounds__(256) void group_gemm(const float* __restrict__ xin,
    const float* __restrict__ neurons, const float* __restrict__ w_all,
    const int* __restrict__ lists, const int* __restrict__ counts,
    float* __restrict__ out) {
  const int COLCH = NCOLT / 256;
  int e = blockIdx.x;
  int cnt = counts[e];
  int base = (blockIdx.y / COLCH) * 64;
  if (base >= cnt) return;
  int colbase = (blockIdx.y % COLCH) * 256;
  ggemm_body<KDIM, NCOLT, TOPK>(xin, neurons + (size_t)e*KDIM*NCOLT,
                                w_all, lists + (size_t)e*BS, cnt, base, colbase, out);
}

// grid: (expert, token_chunk, 3which). NCOLT==256.
template<int KDIM, int NCOLT, int TOPK>
__global__ __launch_bounds__(256) void group_gemm3(const float* __restrict__ xin,
    const float* __restrict__ neurons, const float* __restrict__ w_all,
    const int* __restrict__ lists, const int* __restrict__ counts,
    float* __restrict__ out) {
  int e = blockIdx.x, which = blockIdx.z;
  int cnt = counts[which*64 + e];
  int base = blockIdx.y * 64;
  if (base >= cnt) return;
  ggemm_body<KDIM, NCOLT, TOPK>(xin, neurons + (size_t)e*KDIM*NCOLT,
                                w_all + (size_t)which*BS*TOPK,
                                lists + ((size_t)which*64 + e)*BS, cnt, base, 0,
                                out + (size_t)which*BS*NCOLT);
}

// ------------- Attention: one block per (q, head*batch) -------------
__global__ __launch_bounds__(256) void attn_kernel(const float* __restrict__ Q,
    const float* __restrict__ K, const float* __restrict__ V, float* __restrict__ AO) {
  int qs = blockIdx.x;
  int hb = blockIdx.y; int h = hb & 7, b = hb >> 3;
  int t = threadIdx.x;
  __shared__ float qv[32];
  __shared__ float sc[512];
  __shared__ float red[256];
  const size_t baseQ = ((size_t)(b*512 + qs))*RK + h*DH;
  if (t < 32) qv[t] = Q[baseQ + t];
  __syncthreads();
  int nk = qs + 1;
  const float scale = 0.17677669529663687f;  // 1/sqrt(32)
  for (int k = t; k < nk; k += 256) {
    const float* kr = K + ((size_t)(b*512 + k))*RK + h*DH;
    float s = 0.f;
    #pragma unroll
    for (int d = 0; d < 32; d += 4) {
      float4 kv = *reinterpret_cast<const float4*>(kr + d);
      s += kv.x*qv[d] + kv.y*qv[d+1] + kv.z*qv[d+2] + kv.w*qv[d+3];
    }
    sc[k] = s * scale;
  }
  __syncthreads();
  float m = NEGINF;
  for (int k = t; k < nk; k += 256) m = fmaxf(m, sc[k]);
  red[t] = m; __syncthreads();
  for (int o = 128; o > 0; o >>= 1) { if (t < o) red[t] = fmaxf(red[t], red[t+o]); __syncthreads(); }
  m = red[0];
  __syncthreads();
  float sloc = 0.f;
  for (int k = t; k < nk; k += 256) { float pp = expf(sc[k] - m); sc[k] = pp; sloc += pp; }
  red[t] = sloc; __syncthreads();
  for (int o = 128; o > 0; o >>= 1) { if (t < o) red[t] += red[t+o]; __syncthreads(); }
  float inv = 1.f / red[0];
  __syncthreads();
  int d = t & 31, c = t >> 5;
  float pa = 0.f;
  for (int k = c; k < nk; k += 8)
    pa += sc[k] * V[((size_t)(b*512 + k))*RK + h*DH + d];
  red[c*32 + d] = pa; __syncthreads();
  if (t < 32) {
    float o = 0.f;
    #pragma unroll
    for (int c2 = 0; c2 < 8; ++c2) o += red[c2*32 + t];
    AO[baseQ + t] = o * inv;
  }
}

// ------------- Transpose knowledge_K [8192][256] -> KT [256][8192] -------------
__global__ __launch_bounds__(256) void transpose_k(const float* __restrict__ kK,
                                                   float* __restrict__ KT) {
  __shared__ float tile[32][33];
  int bx = blockIdx.x, by = blockIdx.y;
  int tx = threadIdx.x & 31, ty = threadIdx.x >> 5;
  for (int r = ty; r < 32; r += 8)
    tile[r][tx] = kK[(size_t)(bx*32 + r)*RK + by*32 + tx];
  __syncthreads();
  for (int r = ty; r < 32; r += 8)
    KT[(size_t)(by*32 + r)*NKN + bx*32 + tx] = tile[tx][r];
}

// ------------- Knowledge pass 1: register-tiled scores + per-chunk top-8 -------------
// grid: (32 chunks, 64 token-tiles of 32). Thread: 8 tokens x 4 entries.
__global__ __launch_bounds__(256) void knowledge_score(const float* __restrict__ Qm,
    const float* __restrict__ KT, float* __restrict__ cand_s, int* __restrict__ cand_i) {
  int chunk = blockIdx.x, tile = blockIdx.y, t = threadIdx.x;
  int tx = t & 63, ty = t >> 6;
  __shared__ __align__(16) float qm[32][RK];
  __shared__ float sc[32][256];
  for (int l = t; l < 2048; l += 256) {
    int row = l >> 6, j4 = (l & 63) * 4;
    *reinterpret_cast<float4*>(&qm[row][j4]) =
        *reinterpret_cast<const float4*>(Qm + (size_t)(tile*32 + row)*RK + j4);
  }
  __syncthreads();
  float acc[8][4];
  #pragma unroll
  for (int i = 0; i < 8; ++i)
    #pragma unroll
    for (int c = 0; c < 4; ++c) acc[i][c] = 0.f;
  int e = chunk*256 + tx;
  for (int d = 0; d < RK; d += 4) {
    float kw[4][4];
    #pragma unroll
    for (int kk = 0; kk < 4; ++kk)
      #pragma unroll
      for (int c = 0; c < 4; ++c)
        kw[kk][c] = KT[(size_t)(d+kk)*NKN + e + c*64];
    #pragma unroll
    for (int i = 0; i < 8; ++i) {
      const float4 q4 = *reinterpret_cast<const float4*>(&qm[ty*8 + i][d]);
      #pragma unroll
      for (int c = 0; c < 4; ++c)
        acc[i][c] = fmaf(q4.w, kw[3][c], fmaf(q4.z, kw[2][c],
                    fmaf(q4.y, kw[1][c], fmaf(q4.x, kw[0][c], acc[i][c]))));
    }
  }
  #pragma unroll
  for (int i = 0; i < 8; ++i)
    #pragma unroll
    for (int c = 0; c < 4; ++c)
      sc[ty*8 + i][tx + c*64] = acc[i][c];
  __syncthreads();
  int lane = tx, wv = ty;
  for (int s = 0; s < 8; ++s) {
    int tok = wv*8 + s;
    float v0 = sc[tok][lane], v1 = sc[tok][lane+64], v2 = sc[tok][lane+128], v3 = sc[tok][lane+192];
    size_t cbase = ((size_t)(tile*32 + tok)*KCH + chunk)*KK;
    #pragma unroll
    for (int iter = 0; iter < KK; ++iter) {
      float mv = v0; int mp = lane;
      if (v1 > mv) { mv = v1; mp = lane+64; }
      if (v2 > mv) { mv = v2; mp = lane+128; }
      if (v3 > mv) { mv = v3; mp = lane+192; }
      #pragma unroll
      for (int off = 32; off > 0; off >>= 1) {
        float ov = __shfl_xor(mv, off); int op = __shfl_xor(mp, off);
        if (ov > mv || (ov == mv && op < mp)) { mv = ov; mp = op; }
      }
      if ((mp & 63) == lane) {
        int j = mp >> 6;
        if (j == 0) v0 = NEGINF; else if (j == 1) v1 = NEGINF;
        else if (j == 2) v2 = NEGINF; else v3 = NEGINF;
      }
      if (lane == 0) { cand_s[cbase + iter] = mv; cand_i[cbase + iter] = chunk*256 + mp; }
    }
  }
}

// ------------- Knowledge pass 2: merge candidates -> top-8, softmax, V gather -------------
__global__ __launch_bounds__(256) void knowledge_merge(const float* __restrict__ cand_s,
    const int* __restrict__ cand_i, const float* __restrict__ kV, float* __restrict__ xout) {
  int tok = blockIdx.x, t = threadIdx.x;
  __shared__ float s_sc[256];
  __shared__ int   s_ix[256];
  __shared__ float w8[KK];
  __shared__ int   i8[KK];
  s_sc[t] = cand_s[(size_t)tok*256 + t];
  s_ix[t] = cand_i[(size_t)tok*256 + t];
  __syncthreads();
  if (t < 64) {
    float v0 = s_sc[t], v1 = s_sc[t+64], v2 = s_sc[t+128], v3 = s_sc[t+192];
    float tops[KK]; int tpos[KK];
    #pragma unroll
    for (int iter = 0; iter < KK; ++iter) {
      float mv = v0; int mp = t;
      if (v1 > mv) { mv = v1; mp = t+64; }
      if (v2 > mv) { mv = v2; mp = t+128; }
      if (v3 > mv) { mv = v3; mp = t+192; }
      #pragma unroll
      for (int off = 32; off > 0; off >>= 1) {
        float ov = __shfl_xor(mv, off); int op = __shfl_xor(mp, off);
        if (ov > mv || (ov == mv && op < mp)) { mv = ov; mp = op; }
      }
      tops[iter] = mv; tpos[iter] = mp;
      if ((mp & 63) == t) {
        int j = mp >> 6;
        if (j == 0) v0 = NEGINF; else if (j == 1) v1 = NEGINF;
        else if (j == 2) v2 = NEGINF; else v3 = NEGINF;
      }
    }
    if (t == 0) {
      const float kscale = 1.f/16.f;  // 1/sqrt(256)
      float mx = tops[0]*kscale, se = 0.f, ex[KK];
      #pragma unroll
      for (int k = 0; k < KK; ++k) { ex[k] = expf(tops[k]*kscale - mx); se += ex[k]; }
      float inv = 1.f / se;
      #pragma unroll
      for (int k = 0; k < KK; ++k) { w8[k] = ex[k]*inv; i8[k] = s_ix[tpos[k]]; }
    }
  }
  __syncthreads();
  size_t orow = (size_t)tok * DM;
  float4 o = *reinterpret_cast<const float4*>(xout + orow + t*4);
  #pragma unroll
  for (int k = 0; k < KK; ++k) {
    float w = w8[k];
    const float4 v4 = *reinterpret_cast<const float4*>(kV + (size_t)i8[k]*DM + t*4);
    o.x += w*v4.x; o.y += w*v4.y; o.z += w*v4.z; o.w += w*v4.w;
  }
  *reinterpret_cast<float4*>(xout + orow + t*4) = o;
}

extern "C" void kernel_launch(void* const* d_in, const int* in_sizes, int n_in,
                              void* d_out, int out_size, void* d_ws, size_t ws_size,
                              hipStream_t stream) {
  const float* x  = (const float*)d_in[0];
  const float* cn = (const float*)d_in[2];
  const float* en = (const float*)d_in[3];
  const float* kK = (const float*)d_in[4];
  const float* kV = (const float*)d_in[5];
  const float* rq = (const float*)d_in[6];
  const float* rk = (const float*)d_in[7];
  const float* rv = (const float*)d_in[8];
  const float* ro = (const float*)d_in[9];
  const float* rm = (const float*)d_in[10];
  const float* g1 = (const float*)d_in[11];
  const float* b1 = (const float*)d_in[12];
  const float* g2 = (const float*)d_in[13];
  const float* b2 = (const float*)d_in[14];
  float* out = (float*)d_out;

  char* p = (char*)d_ws;
  auto alloc = [&](size_t bytes) { char* r = p; p += (bytes + 255) & ~(size_t)255; return r; };
  float* h    = (float*)alloc((size_t)BS*DM*4);
  float* h2   = (float*)alloc((size_t)BS*DM*4);
  float* KT   = (float*)alloc((size_t)RK*NKN*4);
  float* Q    = (float*)alloc((size_t)BS*RK*4);   // Q,Kb,Vb,Qm contiguous for one memset
  float* Kb   = (float*)alloc((size_t)BS*RK*4);
  float* Vb   = (float*)alloc((size_t)BS*RK*4);
  float* Qm   = (float*)alloc((size_t)BS*RK*4);
  float* AO   = (float*)alloc((size_t)BS*RK*4);
  float* w_all= (float*)alloc((size_t)3*BS*CK*4);
  float* w_o  = (float*)alloc((size_t)BS*EK*4);
  float* w_m  = (float*)alloc((size_t)BS*CK*4);
  float* cand_s = (float*)alloc((size_t)BS*KCH*KK*4);
  int*   cand_i = (int*)  alloc((size_t)BS*KCH*KK*4);
  int* lists  = (int*)alloc((size_t)5*64*BS*4);   // [q,k,v,o,m]
  int* counts = (int*)alloc((size_t)5*64*4);

  int *listo = lists + 3*64*BS, *listm = lists + 4*64*BS;
  int *co = counts + 192, *cm = counts + 256;

  hipMemsetAsync(counts, 0, 5*64*4, stream);
  hipMemsetAsync(Q, 0, (size_t)BS*RK*4*4, stream);  // zeros Q, Kb, Vb, Qm

  ln_kernel<<<BS, 256, 0, stream>>>(x, g1, b1, h);

  router3<<<BS, 256, 0, stream>>>(h, rq, rk, rv, w_all, lists, counts);
  group_gemm3<DM, RK, CK><<<dim3(64, 32, 3), 256, 0, stream>>>(h, cn, w_all, lists, counts, Q);

  attn_kernel<<<dim3(512, 32), 256, 0, stream>>>(Q, Kb, Vb, AO);

  hipMemcpyAsync(out, x, (size_t)BS*DM*4, hipMemcpyDeviceToDevice, stream);  // out = x

  router_topk<RK, EK><<<BS, 256, 0, stream>>>(AO, ro, w_o, listo, co);
  group_gemm<RK, DM, EK><<<dim3(64, 32*4), 256, 0, stream>>>(AO, en, w_o, listo, co, out); // out = x1

  ln_kernel<<<BS, 256, 0, stream>>>(out, g2, b2, h2);
  router_topk<DM, CK><<<BS, 256, 0, stream>>>(h2, rm, w_m, listm, cm);
  group_gemm<DM, RK, CK><<<dim3(64, 32), 256, 0, stream>>>(h2, cn, w_m, listm, cm, Qm);

  transpose_k<<<dim3(NKN/32, RK/32), 256, 0, stream>>>(kK, KT);
  knowledge_score<<<dim3(KCH, BS/32), 256, 0, stream>>>(Qm, KT, cand_s, cand_i);
  knowledge_merge<<<BS, 256, 0, stream>>>(cand_s, cand_i, kV, out);  // out = x1 + mem_out
}

// Round 4
// 2266.594 us; speedup vs baseline: 3.2049x; 1.2957x over previous
//
#include <hip/hip_runtime.h>

#define BS   2048     // B*S tokens
#define DM   1024     // D_MODEL
#define RK   256      // RANK
#define NKN  8192     // N_KNOWLEDGE
#define CK   8        // COMPRESS_TOP_K
#define EK   4        // EXPAND_TOP_K
#define KK   8        // KNOWLEDGE_K
#define KCH  32       // knowledge chunks of 256

#define NEGINF -1e30f

// ---------------- LayerNorm: one block per row of 1024 ----------------
__global__ __launch_bounds__(256) void ln_kernel(const float* __restrict__ xin,
    const float* __restrict__ g, const float* __restrict__ bb, float* __restrict__ out) {
  int row = blockIdx.x, t = threadIdx.x;
  __shared__ float red[256];
  const float4 v = *reinterpret_cast<const float4*>(xin + (size_t)row*DM + t*4);
  red[t] = v.x + v.y + v.z + v.w;
  __syncthreads();
  for (int o = 128; o > 0; o >>= 1) { if (t < o) red[t] += red[t+o]; __syncthreads(); }
  float mu = red[0] * (1.f/DM);
  __syncthreads();
  float dx = v.x-mu, dy = v.y-mu, dz = v.z-mu, dw = v.w-mu;
  red[t] = dx*dx + dy*dy + dz*dz + dw*dw;
  __syncthreads();
  for (int o = 128; o > 0; o >>= 1) { if (t < o) red[t] += red[t+o]; __syncthreads(); }
  float rs = rsqrtf(red[0]*(1.f/DM) + 1e-5f);
  float4 gv = *reinterpret_cast<const float4*>(g + t*4);
  float4 bv = *reinterpret_cast<const float4*>(bb + t*4);
  float4 o4 = make_float4(dx*rs*gv.x+bv.x, dy*rs*gv.y+bv.y, dz*rs*gv.z+bv.z, dw*rs*gv.w+bv.w);
  *reinterpret_cast<float4*>(out + (size_t)row*DM + t*4) = o4;
}

// ---- wave-parallel top-k over 64 scores held one-per-lane ----
template<int TOPK>
__device__ inline void wave_topk64(float bv, int lane, float* tops, int* tidx) {
  #pragma unroll
  for (int k = 0; k < TOPK; ++k) {
    float mv = bv; int mp = lane;
    #pragma unroll
    for (int off = 32; off > 0; off >>= 1) {
      float ov = __shfl_xor(mv, off); int op = __shfl_xor(mp, off);
      if (ov > mv || (ov == mv && op < mp)) { mv = ov; mp = op; }
    }
    tops[k] = mv; tidx[k] = mp;
    if (lane == mp) bv = NEGINF;
  }
}

// ------------- Generic router -------------
template<int DIM, int TOPK>
__global__ __launch_bounds__(256) void router_topk(const float* __restrict__ xin,
    const float* __restrict__ rw, float* __restrict__ w_out,
    int* __restrict__ lists, int* __restrict__ counts) {
  int token = blockIdx.x, t = threadIdx.x;
  __shared__ float part[4][64];
  int n = t & 63, c = t >> 6;
  const int CH = DIM / 4;
  const float* xr = xin + (size_t)token*DIM + c*CH;
  const float* wr = rw  + (size_t)n*DIM + c*CH;
  float p = 0.f;
  for (int j = 0; j < CH; j += 4) {
    float4 a = *reinterpret_cast<const float4*>(xr + j);
    float4 b = *reinterpret_cast<const float4*>(wr + j);
    p += a.x*b.x + a.y*b.y + a.z*b.z + a.w*b.w;
  }
  part[c][n] = p;
  __syncthreads();
  if (t < 64) {
    float bv = part[0][t] + part[1][t] + part[2][t] + part[3][t];
    float tops[TOPK]; int tidx[TOPK];
    wave_topk64<TOPK>(bv, t, tops, tidx);
    if (t == 0) {
      float mx = tops[0], se = 0.f, ex[TOPK];
      #pragma unroll
      for (int k = 0; k < TOPK; ++k) { ex[k] = expf(tops[k] - mx); se += ex[k]; }
      float inv = 1.f / se;
      #pragma unroll
      for (int k = 0; k < TOPK; ++k) {
        w_out[token*TOPK + k] = ex[k] * inv;
        int pos = atomicAdd(&counts[tidx[k]], 1);
        lists[tidx[k]*BS + pos] = token*TOPK + k;
      }
    }
  }
}

// ------------- Fused QKV router -------------
__global__ __launch_bounds__(256) void router3(const float* __restrict__ xin,
    const float* __restrict__ w0, const float* __restrict__ w1, const float* __restrict__ w2,
    float* __restrict__ w_all, int* __restrict__ lists, int* __restrict__ counts) {
  int token = blockIdx.x, t = threadIdx.x;
  __shared__ float part[3][4][64];
  int n = t & 63, c = t >> 6;
  const int CH = DM / 4;
  const float* xr = xin + (size_t)token*DM + c*CH;
  const float* a0 = w0 + (size_t)n*DM + c*CH;
  const float* a1 = w1 + (size_t)n*DM + c*CH;
  const float* a2 = w2 + (size_t)n*DM + c*CH;
  float p0 = 0.f, p1 = 0.f, p2 = 0.f;
  for (int j = 0; j < CH; j += 4) {
    float4 a  = *reinterpret_cast<const float4*>(xr + j);
    float4 b0 = *reinterpret_cast<const float4*>(a0 + j);
    float4 b1 = *reinterpret_cast<const float4*>(a1 + j);
    float4 b2 = *reinterpret_cast<const float4*>(a2 + j);
    p0 += a.x*b0.x + a.y*b0.y + a.z*b0.z + a.w*b0.w;
    p1 += a.x*b1.x + a.y*b1.y + a.z*b1.z + a.w*b1.w;
    p2 += a.x*b2.x + a.y*b2.y + a.z*b2.z + a.w*b2.w;
  }
  part[0][c][n] = p0; part[1][c][n] = p1; part[2][c][n] = p2;
  __syncthreads();
  int wv = t >> 6, lane = t & 63;
  if (wv < 3) {
    float bv = part[wv][0][lane] + part[wv][1][lane] + part[wv][2][lane] + part[wv][3][lane];
    float tops[CK]; int tidx[CK];
    wave_topk64<CK>(bv, lane, tops, tidx);
    if (lane == 0) {
      float* wo = w_all + (size_t)wv*BS*CK;
      int* lst  = lists  + (size_t)wv*64*BS;
      int* cnt  = counts + wv*64;
      float mx = tops[0], se = 0.f, ex[CK];
      #pragma unroll
      for (int k = 0; k < CK; ++k) { ex[k] = expf(tops[k] - mx); se += ex[k]; }
      float inv = 1.f / se;
      #pragma unroll
      for (int k = 0; k < CK; ++k) {
        wo[token*CK + k] = ex[k] * inv;
        int pos = atomicAdd(&cnt[tidx[k]], 1);
        lst[tidx[k]*BS + pos] = token*CK + k;
      }
    }
  }
}

// ------------- Grouped expert SGEMM: 64 tok x 256 col block, BK=32, 8x8/thread -------------
// grid: (expert, token_chunk16, which*COLCH + cc)
template<int KDIM, int NCOLT, int TK>
__global__ __launch_bounds__(256) void ggemm_f32(const float* __restrict__ xin,
    const float* __restrict__ neurons, const float* __restrict__ w_all,
    const int* __restrict__ lists, const int* __restrict__ counts,
    float* __restrict__ out) {
  constexpr int COLCH = NCOLT / 256;
  int e = blockIdx.x;
  int which = blockIdx.z / COLCH, cc = blockIdx.z % COLCH;
  int cnt = counts[which*64 + e];
  int base = blockIdx.y * 64;
  if (base >= cnt) return;
  const int* list_e = lists + ((size_t)which*64 + e)*BS;
  const float* wvp = w_all + (size_t)which*BS*TK;
  int t = threadIdx.x;
  __shared__ __align__(16) float Bs[32][256];
  __shared__ __align__(16) float At[32][64];
  __shared__ int   toks[64];
  __shared__ float wts[64];
  if (t < 64) {
    int idx = base + t;
    if (idx < cnt) { int e2 = list_e[idx]; toks[t] = e2 / TK; wts[t] = wvp[e2]; }
    else           { toks[t] = -1; wts[t] = 0.f; }
  }
  __syncthreads();
  float acc[8][8];
  #pragma unroll
  for (int i = 0; i < 8; ++i)
    #pragma unroll
    for (int j = 0; j < 8; ++j) acc[i][j] = 0.f;
  int tr = t >> 5, tc = t & 31;
  const float* W = neurons + (size_t)e*KDIM*NCOLT + cc*256;
  for (int k0 = 0; k0 < KDIM; k0 += 32) {
    // stage B tile [32 k][256 col]: coalesced float4 -> linear LDS
    #pragma unroll
    for (int it = 0; it < 8; ++it) {
      int f = it*1024 + t*4;
      int row = f >> 8, col = f & 255;
      float4 v = *reinterpret_cast<const float4*>(W + (size_t)(k0+row)*NCOLT + col);
      *reinterpret_cast<float4*>(&Bs[row][col]) = v;
    }
    // stage A tile transposed [32 k][64 tok]: gathered float4 -> 4 scalar LDS writes
    #pragma unroll
    for (int it = 0; it < 2; ++it) {
      int l = t + it*256;
      int r = l & 63, kc = (l >> 6) * 4;
      int tok = toks[r];
      float4 v = (tok >= 0)
          ? *reinterpret_cast<const float4*>(xin + (size_t)tok*KDIM + k0 + kc)
          : make_float4(0.f, 0.f, 0.f, 0.f);
      At[kc+0][r] = v.x; At[kc+1][r] = v.y; At[kc+2][r] = v.z; At[kc+3][r] = v.w;
    }
    __syncthreads();
    #pragma unroll 4
    for (int kk = 0; kk < 32; ++kk) {
      float4 a0 = *reinterpret_cast<const float4*>(&At[kk][tr*8]);
      float4 a1 = *reinterpret_cast<const float4*>(&At[kk][tr*8 + 4]);
      float4 b0 = *reinterpret_cast<const float4*>(&Bs[kk][tc*8]);
      float4 b1 = *reinterpret_cast<const float4*>(&Bs[kk][tc*8 + 4]);
      float a[8] = {a0.x,a0.y,a0.z,a0.w,a1.x,a1.y,a1.z,a1.w};
      float b[8] = {b0.x,b0.y,b0.z,b0.w,b1.x,b1.y,b1.z,b1.w};
      #pragma unroll
      for (int i = 0; i < 8; ++i)
        #pragma unroll
        for (int j = 0; j < 8; ++j)
          acc[i][j] = fmaf(a[i], b[j], acc[i][j]);
    }
    __syncthreads();
  }
  #pragma unroll
  for (int i = 0; i < 8; ++i) {
    int r = tr*8 + i;
    int tok = toks[r];
    if (tok < 0) continue;
    float wt = wts[r];
    float* orow = out + ((size_t)which*BS + tok)*NCOLT + cc*256 + tc*8;
    #pragma unroll
    for (int j = 0; j < 8; ++j) atomicAdd(&orow[j], wt * acc[i][j]);
  }
}

// ------------- Attention: one block per (q, head*batch) -------------
__global__ __launch_bounds__(256) void attn_kernel(const float* __restrict__ Q,
    const float* __restrict__ K, const float* __restrict__ V, float* __restrict__ AO) {
  int qs = blockIdx.x;
  int hb = blockIdx.y; int h = hb & 7, b = hb >> 3;
  int t = threadIdx.x;
  __shared__ float qv[32];
  __shared__ float sc[512];
  __shared__ float red[256];
  const size_t baseQ = ((size_t)(b*512 + qs))*RK + h*32;
  if (t < 32) qv[t] = Q[baseQ + t];
  __syncthreads();
  int nk = qs + 1;
  const float scale = 0.17677669529663687f;  // 1/sqrt(32)
  for (int k = t; k < nk; k += 256) {
    const float* kr = K + ((size_t)(b*512 + k))*RK + h*32;
    float s = 0.f;
    #pragma unroll
    for (int d = 0; d < 32; d += 4) {
      float4 kv = *reinterpret_cast<const float4*>(kr + d);
      s += kv.x*qv[d] + kv.y*qv[d+1] + kv.z*qv[d+2] + kv.w*qv[d+3];
    }
    sc[k] = s * scale;
  }
  __syncthreads();
  float m = NEGINF;
  for (int k = t; k < nk; k += 256) m = fmaxf(m, sc[k]);
  red[t] = m; __syncthreads();
  for (int o = 128; o > 0; o >>= 1) { if (t < o) red[t] = fmaxf(red[t], red[t+o]); __syncthreads(); }
  m = red[0];
  __syncthreads();
  float sloc = 0.f;
  for (int k = t; k < nk; k += 256) { float pp = expf(sc[k] - m); sc[k] = pp; sloc += pp; }
  red[t] = sloc; __syncthreads();
  for (int o = 128; o > 0; o >>= 1) { if (t < o) red[t] += red[t+o]; __syncthreads(); }
  float inv = 1.f / red[0];
  __syncthreads();
  int d = t & 31, c = t >> 5;
  float pa = 0.f;
  for (int k = c; k < nk; k += 8)
    pa += sc[k] * V[((size_t)(b*512 + k))*RK + h*32 + d];
  red[c*32 + d] = pa; __syncthreads();
  if (t < 32) {
    float o = 0.f;
    #pragma unroll
    for (int c2 = 0; c2 < 8; ++c2) o += red[c2*32 + t];
    AO[baseQ + t] = o * inv;
  }
}

// ------------- Transpose knowledge_K [8192][256] -> KT [256][8192] -------------
__global__ __launch_bounds__(256) void transpose_k(const float* __restrict__ kK,
                                                   float* __restrict__ KT) {
  __shared__ float tile[32][33];
  int bx = blockIdx.x, by = blockIdx.y;
  int tx = threadIdx.x & 31, ty = threadIdx.x >> 5;
  for (int r = ty; r < 32; r += 8)
    tile[r][tx] = kK[(size_t)(bx*32 + r)*RK + by*32 + tx];
  __syncthreads();
  for (int r = ty; r < 32; r += 8)
    KT[(size_t)(by*32 + r)*NKN + bx*32 + tx] = tile[tx][r];
}

// ------------- Knowledge scores: SGEMM 64 tok x 256 entries + per-chunk top-8 -------------
// grid: (32 chunks, 32 token-tiles of 64)
__global__ __launch_bounds__(256) void kscore(const float* __restrict__ Qm,
    const float* __restrict__ KT, float* __restrict__ cand_s, int* __restrict__ cand_i) {
  int chunk = blockIdx.x, tile = blockIdx.y, t = threadIdx.x;
  __shared__ __align__(16) char smem[64*258*4];  // 66048 B arena
  float (*Bs)[256] = reinterpret_cast<float(*)[256]>(smem);
  float (*At)[64]  = reinterpret_cast<float(*)[64]>(smem + 32*256*4);
  float (*sc)[258] = reinterpret_cast<float(*)[258]>(smem);
  float acc[8][8];
  #pragma unroll
  for (int i = 0; i < 8; ++i)
    #pragma unroll
    for (int j = 0; j < 8; ++j) acc[i][j] = 0.f;
  int tr = t >> 5, tc = t & 31;
  for (int k0 = 0; k0 < RK; k0 += 32) {
    #pragma unroll
    for (int it = 0; it < 8; ++it) {
      int f = it*1024 + t*4;
      int row = f >> 8, col = f & 255;
      float4 v = *reinterpret_cast<const float4*>(KT + (size_t)(k0+row)*NKN + chunk*256 + col);
      *reinterpret_cast<float4*>(&Bs[row][col]) = v;
    }
    #pragma unroll
    for (int it = 0; it < 2; ++it) {
      int l = t + it*256;
      int r = l & 63, kc = (l >> 6) * 4;
      float4 v = *reinterpret_cast<const float4*>(Qm + (size_t)(tile*64 + r)*RK + k0 + kc);
      At[kc+0][r] = v.x; At[kc+1][r] = v.y; At[kc+2][r] = v.z; At[kc+3][r] = v.w;
    }
    __syncthreads();
    #pragma unroll 4
    for (int kk = 0; kk < 32; ++kk) {
      float4 a0 = *reinterpret_cast<const float4*>(&At[kk][tr*8]);
      float4 a1 = *reinterpret_cast<const float4*>(&At[kk][tr*8 + 4]);
      float4 b0 = *reinterpret_cast<const float4*>(&Bs[kk][tc*8]);
      float4 b1 = *reinterpret_cast<const float4*>(&Bs[kk][tc*8 + 4]);
      float a[8] = {a0.x,a0.y,a0.z,a0.w,a1.x,a1.y,a1.z,a1.w};
      float b[8] = {b0.x,b0.y,b0.z,b0.w,b1.x,b1.y,b1.z,b1.w};
      #pragma unroll
      for (int i = 0; i < 8; ++i)
        #pragma unroll
        for (int j = 0; j < 8; ++j)
          acc[i][j] = fmaf(a[i], b[j], acc[i][j]);
    }
    __syncthreads();
  }
  // spill scores to LDS (arena reuse is safe: barrier above)
  #pragma unroll
  for (int i = 0; i < 8; ++i)
    #pragma unroll
    for (int j = 0; j < 8; ++j)
      sc[tr*8 + i][tc*8 + j] = acc[i][j];
  __syncthreads();
  // per-token top-8 over this chunk's 256 entries
  int lane = t & 63, wv = t >> 6;
  for (int s = 0; s < 16; ++s) {
    int tok = wv*16 + s;
    float v0 = sc[tok][lane], v1 = sc[tok][lane+64], v2 = sc[tok][lane+128], v3 = sc[tok][lane+192];
    size_t cbase = ((size_t)(tile*64 + tok)*KCH + chunk)*KK;
    #pragma unroll
    for (int iter = 0; iter < KK; ++iter) {
      float mv = v0; int mp = lane;
      if (v1 > mv) { mv = v1; mp = lane+64; }
      if (v2 > mv) { mv = v2; mp = lane+128; }
      if (v3 > mv) { mv = v3; mp = lane+192; }
      #pragma unroll
      for (int off = 32; off > 0; off >>= 1) {
        float ov = __shfl_xor(mv, off); int op = __shfl_xor(mp, off);
        if (ov > mv || (ov == mv && op < mp)) { mv = ov; mp = op; }
      }
      if ((mp & 63) == lane) {
        int j = mp >> 6;
        if (j == 0) v0 = NEGINF; else if (j == 1) v1 = NEGINF;
        else if (j == 2) v2 = NEGINF; else v3 = NEGINF;
      }
      if (lane == 0) { cand_s[cbase + iter] = mv; cand_i[cbase + iter] = chunk*256 + mp; }
    }
  }
}

// ------------- Knowledge merge: 256 candidates -> top-8, softmax, V gather -------------
__global__ __launch_bounds__(256) void knowledge_merge(const float* __restrict__ cand_s,
    const int* __restrict__ cand_i, const float* __restrict__ kV, float* __restrict__ xout) {
  int tok = blockIdx.x, t = threadIdx.x;
  __shared__ float s_sc[256];
  __shared__ int   s_ix[256];
  __shared__ float w8[KK];
  __shared__ int   i8[KK];
  s_sc[t] = cand_s[(size_t)tok*256 + t];
  s_ix[t] = cand_i[(size_t)tok*256 + t];
  __syncthreads();
  if (t < 64) {
    float v0 = s_sc[t], v1 = s_sc[t+64], v2 = s_sc[t+128], v3 = s_sc[t+192];
    float tops[KK]; int tpos[KK];
    #pragma unroll
    for (int iter = 0; iter < KK; ++iter) {
      float mv = v0; int mp = t;
      if (v1 > mv) { mv = v1; mp = t+64; }
      if (v2 > mv) { mv = v2; mp = t+128; }
      if (v3 > mv) { mv = v3; mp = t+192; }
      #pragma unroll
      for (int off = 32; off > 0; off >>= 1) {
        float ov = __shfl_xor(mv, off); int op = __shfl_xor(mp, off);
        if (ov > mv || (ov == mv && op < mp)) { mv = ov; mp = op; }
      }
      tops[iter] = mv; tpos[iter] = mp;
      if ((mp & 63) == t) {
        int j = mp >> 6;
        if (j == 0) v0 = NEGINF; else if (j == 1) v1 = NEGINF;
        else if (j == 2) v2 = NEGINF; else v3 = NEGINF;
      }
    }
    if (t == 0) {
      const float kscale = 1.f/16.f;  // 1/sqrt(256)
      float mx = tops[0]*kscale, se = 0.f, ex[KK];
      #pragma unroll
      for (int k = 0; k < KK; ++k) { ex[k] = expf(tops[k]*kscale - mx); se += ex[k]; }
      float inv = 1.f / se;
      #pragma unroll
      for (int k = 0; k < KK; ++k) { w8[k] = ex[k]*inv; i8[k] = s_ix[tpos[k]]; }
    }
  }
  __syncthreads();
  size_t orow = (size_t)tok * DM;
  float4 o = *reinterpret_cast<const float4*>(xout + orow + t*4);
  #pragma unroll
  for (int k = 0; k < KK; ++k) {
    float w = w8[k];
    const float4 v4 = *reinterpret_cast<const float4*>(kV + (size_t)i8[k]*DM + t*4);
    o.x += w*v4.x; o.y += w*v4.y; o.z += w*v4.z; o.w += w*v4.w;
  }
  *reinterpret_cast<float4*>(xout + orow + t*4) = o;
}

extern "C" void kernel_launch(void* const* d_in, const int* in_sizes, int n_in,
                              void* d_out, int out_size, void* d_ws, size_t ws_size,
                              hipStream_t stream) {
  const float* x  = (const float*)d_in[0];
  const float* cn = (const float*)d_in[2];
  const float* en = (const float*)d_in[3];
  const float* kK = (const float*)d_in[4];
  const float* kV = (const float*)d_in[5];
  const float* rq = (const float*)d_in[6];
  const float* rk = (const float*)d_in[7];
  const float* rv = (const float*)d_in[8];
  const float* ro = (const float*)d_in[9];
  const float* rm = (const float*)d_in[10];
  const float* g1 = (const float*)d_in[11];
  const float* b1 = (const float*)d_in[12];
  const float* g2 = (const float*)d_in[13];
  const float* b2 = (const float*)d_in[14];
  float* out = (float*)d_out;

  char* p = (char*)d_ws;
  auto alloc = [&](size_t bytes) { char* r = p; p += (bytes + 255) & ~(size_t)255; return r; };
  float* h    = (float*)alloc((size_t)BS*DM*4);
  float* h2   = (float*)alloc((size_t)BS*DM*4);
  float* KT   = (float*)alloc((size_t)RK*NKN*4);
  float* Q    = (float*)alloc((size_t)BS*RK*4);   // Q,Kb,Vb,Qm contiguous for one memset
  float* Kb   = (float*)alloc((size_t)BS*RK*4);
  float* Vb   = (float*)alloc((size_t)BS*RK*4);
  float* Qm   = (float*)alloc((size_t)BS*RK*4);
  float* AO   = (float*)alloc((size_t)BS*RK*4);
  float* w_all= (float*)alloc((size_t)3*BS*CK*4);
  float* w_o  = (float*)alloc((size_t)BS*EK*4);
  float* w_m  = (float*)alloc((size_t)BS*CK*4);
  float* cand_s = (float*)alloc((size_t)BS*KCH*KK*4);
  int*   cand_i = (int*)  alloc((size_t)BS*KCH*KK*4);
  int* lists  = (int*)alloc((size_t)5*64*BS*4);   // [q,k,v,o,m]
  int* counts = (int*)alloc((size_t)5*64*4);

  int *listo = lists + 3*64*BS, *listm = lists + 4*64*BS;
  int *co = counts + 192, *cm = counts + 256;

  hipMemsetAsync(counts, 0, 5*64*4, stream);
  hipMemsetAsync(Q, 0, (size_t)BS*RK*4*4, stream);  // zeros Q, Kb, Vb, Qm

  ln_kernel<<<BS, 256, 0, stream>>>(x, g1, b1, h);

  router3<<<BS, 256, 0, stream>>>(h, rq, rk, rv, w_all, lists, counts);
  ggemm_f32<DM, RK, CK><<<dim3(64, 16, 3), 256, 0, stream>>>(h, cn, w_all, lists, counts, Q);

  attn_kernel<<<dim3(512, 32), 256, 0, stream>>>(Q, Kb, Vb, AO);

  hipMemcpyAsync(out, x, (size_t)BS*DM*4, hipMemcpyDeviceToDevice, stream);  // out = x

  router_topk<RK, EK><<<BS, 256, 0, stream>>>(AO, ro, w_o, listo, co);
  ggemm_f32<RK, DM, EK><<<dim3(64, 16, 4), 256, 0, stream>>>(AO, en, w_o, listo, co, out); // out = x1

  ln_kernel<<<BS, 256, 0, stream>>>(out, g2, b2, h2);
  router_topk<DM, CK><<<BS, 256, 0, stream>>>(h2, rm, w_m, listm, cm);
  ggemm_f32<DM, RK, CK><<<dim3(64, 16, 1), 256, 0, stream>>>(h2, cn, w_m, listm, cm, Qm);

  transpose_k<<<dim3(NKN/32, RK/32), 256, 0, stream>>>(kK, KT);
  kscore<<<dim3(KCH, BS/64), 256, 0, stream>>>(Qm, KT, cand_s, cand_i);
  knowledge_merge<<<BS, 256, 0, stream>>>(cand_s, cand_i, kV, out);  // out = x1 + mem_out
}